// Round 7
// baseline (778.774 us; speedup 1.0000x reference)
//
#include <hip/hip_runtime.h>
#include <math.h>

// NoisyTopkRouter: B=4 S=4096 D=2048 E=16 K=2, TEMPERATURE=1. rows = 16384.
// out layout (fp32): router_output [16384*16] | indices-as-float [16384*2] | aux_loss [1]
// Round 7: 256 blocks x 64 rows, 16 waves x 128-d slice, 1024-thread blocks.
//  - R=8 rows/thread, C=4 cols/thread (issue-cost model: 2 + 12/C + 16/R).
//  - W prefetch DISTANCE 2 in 8-d chunks: wp[2][8] float4; chunk k+2 issued while
//    k computes -> ~300 cyc cover >= L2 latency (round-5/6 stall fix).
//  - plain __launch_bounds__(1024): NO waves-per-EU arg. Empirical (r2/r5/r6):
//    second arg 4 => 64-VGPR cap => scratch spill when demand ~95 (50MB writes).
//  - x dbuf LDS [2][64][8] per wave (64KB total), register prefetch, no barriers
//    in main loop; all register-array indices static (macro literal slots).

#define DDIM 2048
#define NEXP 16
#define RPB 64             // rows per block
#define WAVE_D 128         // d-slice per wave (16 waves cover 2048)
#define NCHNK 16           // 8-d chunks per wave slice
#define IDX_OFF 262144
#define AUX_OFF 294912
#define NBLK 256

__global__ __launch_bounds__(1024) void router_main_k(
    const float* __restrict__ x, const float* __restrict__ wr,
    const float* __restrict__ br, const float* __restrict__ wn,
    const float* __restrict__ bn, const float* __restrict__ eps,
    float* __restrict__ out, float* __restrict__ wsp) {
  __shared__ float smem[16384];  // 65536 B: 16 x-dbuf regions / 8 reduce regions

  const int tid  = threadIdx.x;
  const int wave = tid >> 6;
  const int lane = tid & 63;
  const int rg   = lane >> 3;        // 0..7 -> rows {rg + 8i}, i = 0..7
  const int q    = lane & 7;         // col group: q<4 route cols 4q..; q>=4 noise
  const int row_base = blockIdx.x * RPB;

  float* xregion = smem + wave * 1024;   // [2][64][8] dbuf x slice

  // ---- x staging map: lane covers f4 #lane and #(lane+64) of each 128-f4 chunk
  const float* xg0 = x + (size_t)(row_base + (lane >> 1)) * DDIM + wave * WAVE_D + (lane & 1) * 4;
  const float* xg1 = xg0 + (size_t)32 * DDIM;
  const int ls0 = lane * 4;
  const int ls1 = lane * 4 + 256;

  // ---- per-lane W pointer (route for q<4, noise for q>=4)
  const float* wbase = (q < 4 ? wr : wn) + (size_t)(wave * WAVE_D) * NEXP + (q & 3) * 4;

  float4 acc[8];
  #pragma unroll
  for (int i = 0; i < 8; ++i) acc[i] = make_float4(0.f, 0.f, 0.f, 0.f);

  float4 wp[2][8];   // 2-chunk-deep W pipeline (8-d chunks; static slot indices)
  float4 xp0, xp1;

  // ---- prologue: W chunks 0,1 + x chunk 0 ----
  #pragma unroll
  for (int j = 0; j < 8; ++j) wp[0][j] = *(const float4*)(wbase + j * NEXP);
  #pragma unroll
  for (int j = 0; j < 8; ++j) wp[1][j] = *(const float4*)(wbase + (8 + j) * NEXP);
  xp0 = *(const float4*)(xg0);
  xp1 = *(const float4*)(xg1);
  *(float4*)(xregion + ls0) = xp0;
  *(float4*)(xregion + ls1) = xp1;

  // 16 fmaf for one (row i, 4-d subgroup GG) against W slot S
#define FMA_ROW(S, GG, i) { \
    const float4 xv = *(const float4*)(xb + (rg + 8 * (i)) * 8 + ((GG) << 2)); \
    acc[i].x = fmaf(xv.w, wp[S][(GG)*4+3].x, fmaf(xv.z, wp[S][(GG)*4+2].x, fmaf(xv.y, wp[S][(GG)*4+1].x, fmaf(xv.x, wp[S][(GG)*4+0].x, acc[i].x)))); \
    acc[i].y = fmaf(xv.w, wp[S][(GG)*4+3].y, fmaf(xv.z, wp[S][(GG)*4+2].y, fmaf(xv.y, wp[S][(GG)*4+1].y, fmaf(xv.x, wp[S][(GG)*4+0].y, acc[i].y)))); \
    acc[i].z = fmaf(xv.w, wp[S][(GG)*4+3].z, fmaf(xv.z, wp[S][(GG)*4+2].z, fmaf(xv.y, wp[S][(GG)*4+1].z, fmaf(xv.x, wp[S][(GG)*4+0].z, acc[i].z)))); \
    acc[i].w = fmaf(xv.w, wp[S][(GG)*4+3].w, fmaf(xv.z, wp[S][(GG)*4+2].w, fmaf(xv.y, wp[S][(GG)*4+1].w, fmaf(xv.x, wp[S][(GG)*4+0].w, acc[i].w)))); }

#define CHUNK_BODY(K, S) { \
    const float* xb = xregion + (S) * 512; \
    /* x prefetch chunk K+1 (consumed after both subgroups) */ \
    if ((K) + 1 < NCHNK) { \
      xp0 = *(const float4*)(xg0 + ((K) + 1) * 8); \
      xp1 = *(const float4*)(xg1 + ((K) + 1) * 8); \
    } \
    _Pragma("unroll") for (int i = 0; i < 8; ++i) FMA_ROW(S, 0, i); \
    /* refill first half of slot S with W chunk K+2 (consumed its data) */ \
    if ((K) + 2 < NCHNK) { \
      const float* wl = wbase + (size_t)((K) + 2) * 8 * NEXP; \
      _Pragma("unroll") for (int j = 0; j < 4; ++j) wp[S][j] = *(const float4*)(wl + j * NEXP); \
    } \
    _Pragma("unroll") for (int i = 0; i < 8; ++i) FMA_ROW(S, 1, i); \
    if ((K) + 2 < NCHNK) { \
      const float* wl = wbase + (size_t)((K) + 2) * 8 * NEXP; \
      _Pragma("unroll") for (int j = 4; j < 8; ++j) wp[S][j] = *(const float4*)(wl + j * NEXP); \
    } \
    if ((K) + 1 < NCHNK) { \
      float* xw = xregion + (((S) ^ 1)) * 512; \
      *(float4*)(xw + ls0) = xp0; \
      *(float4*)(xw + ls1) = xp1; \
    } }

  for (int k = 0; k < NCHNK; k += 2) {
    CHUNK_BODY(k, 0);
    CHUNK_BODY(k + 1, 1);
  }

  // ---- 16-wave tree reduction over 8 x [64][32] regions (swizzled col ^ row) ----
  const int psw = (q ^ rg) << 2;   // conflict-free: 8 rg-lanes -> 8 distinct bank quads

#define DUMP_R(Rg) { float* pr = smem + (Rg) * 2048; \
    _Pragma("unroll") for (int i = 0; i < 8; ++i) \
      *(float4*)(pr + (rg + 8 * i) * 32 + psw) = acc[i]; }
#define ADD_R(Rg) { const float* pr = smem + (Rg) * 2048; \
    _Pragma("unroll") for (int i = 0; i < 8; ++i) { \
      float4 a = *(const float4*)(pr + (rg + 8 * i) * 32 + psw); \
      acc[i].x += a.x; acc[i].y += a.y; acc[i].z += a.z; acc[i].w += a.w; } }

  __syncthreads();
  if (wave >= 8) DUMP_R(wave - 8);
  __syncthreads();
  if (wave < 8)  ADD_R(wave);
  __syncthreads();
  if (wave >= 4 && wave < 8) DUMP_R(wave - 4);
  __syncthreads();
  if (wave < 4)  ADD_R(wave);
  __syncthreads();
  if (wave >= 2 && wave < 4) DUMP_R(wave - 2);
  __syncthreads();
  if (wave < 2)  ADD_R(wave);
  __syncthreads();
  if (wave == 1) DUMP_R(0);
  __syncthreads();

  // ---- wave 0: final add, dump, per-row epilogue (64 rows on 64 lanes) ----
  if (wave == 0) {
    ADD_R(0);
    DUMP_R(0);   // same-wave ds_write -> ds_read: compiler inserts lgkmcnt waits

    const int row_l = lane;
    const int row_g = row_base + row_l;
    float c[32];
    #pragma unroll
    for (int g = 0; g < 8; ++g) {
      float4 a = *(const float4*)(smem + row_l * 32 + ((g ^ (row_l & 7)) << 2));
      c[g * 4 + 0] = a.x; c[g * 4 + 1] = a.y; c[g * 4 + 2] = a.z; c[g * 4 + 3] = a.w;
    }

    float brv[16], bnv[16], ev[16];
    #pragma unroll
    for (int g = 0; g < 4; ++g) {
      *(float4*)(brv + g * 4) = *(const float4*)(br + g * 4);
      *(float4*)(bnv + g * 4) = *(const float4*)(bn + g * 4);
      *(float4*)(ev  + g * 4) = *(const float4*)(eps + (size_t)row_g * NEXP + g * 4);
    }

    float s[16];
    #pragma unroll
    for (int e = 0; e < 16; ++e) {
      float lg = c[e] + brv[e];
      float nz = c[16 + e] + bnv[e];
      float sp = fmaxf(nz, 0.f) + log1pf(expf(-fabsf(nz)));  // stable softplus
      s[e] = lg + ev[e] * sp;                                 // TEMPERATURE == 1
    }

    // top-2 (ties -> lowest index, matching lax.top_k)
    float b1 = s[0]; int i1 = 0;
    #pragma unroll
    for (int e = 1; e < 16; ++e) { if (s[e] > b1) { b1 = s[e]; i1 = e; } }
    float b2 = -INFINITY; int i2 = 0;
    #pragma unroll
    for (int e = 0; e < 16; ++e) { if (e != i1 && s[e] > b2) { b2 = s[e]; i2 = e; } }

    float t2 = expf(b2 - b1);
    float p1 = 1.f / (1.f + t2);
    float p2 = t2 / (1.f + t2);

    float v[16];
    #pragma unroll
    for (int e = 0; e < 16; ++e)
      v[e] = (e == i1) ? p1 : ((e == i2) ? p2 : 0.f);

    float* orow = out + (size_t)row_g * NEXP;
    *(float4*)(orow + 0)  = make_float4(v[0], v[1], v[2], v[3]);
    *(float4*)(orow + 4)  = make_float4(v[4], v[5], v[6], v[7]);
    *(float4*)(orow + 8)  = make_float4(v[8], v[9], v[10], v[11]);
    *(float4*)(orow + 12) = make_float4(v[12], v[13], v[14], v[15]);

    float* oidx = out + IDX_OFF + (size_t)row_g * 2;
    *(float2*)oidx = make_float2((float)i1, (float)i2);

    // per-block expert-prob sums over 64 rows (full-wave butterfly)
    #pragma unroll
    for (int m = 1; m < 64; m <<= 1) {
      #pragma unroll
      for (int e = 0; e < 16; ++e) v[e] += __shfl_xor(v[e], m, 64);
    }
    if (lane == 0) {
      float* wpo = wsp + (size_t)blockIdx.x * 16;
      *(float4*)(wpo + 0)  = make_float4(v[0], v[1], v[2], v[3]);
      *(float4*)(wpo + 4)  = make_float4(v[4], v[5], v[6], v[7]);
      *(float4*)(wpo + 8)  = make_float4(v[8], v[9], v[10], v[11]);
      *(float4*)(wpo + 12) = make_float4(v[12], v[13], v[14], v[15]);
    }
  }
}

__global__ void router_aux_k(const float* __restrict__ wsp, float* __restrict__ out_aux) {
  __shared__ float red[16][17];
  __shared__ float sq[16];
  const int t = threadIdx.x;
  const int e = t & 15;
  const int g = t >> 4;
  float ssum = 0.f;
  #pragma unroll
  for (int b = 0; b < 16; ++b) ssum += wsp[(size_t)(g * 16 + b) * 16 + e];
  red[g][e] = ssum;
  __syncthreads();
  if (t < 16) {
    float tot = 0.f;
    #pragma unroll
    for (int gg = 0; gg < 16; ++gg) tot += red[gg][t];
    float diff = tot * (1.f / 16384.f) - 0.0625f;
    sq[t] = diff * diff;
  }
  __syncthreads();
  if (t == 0) {
    float a = 0.f;
    #pragma unroll
    for (int i = 0; i < 16; ++i) a += sq[i];
    *out_aux = a;
  }
}

extern "C" void kernel_launch(void* const* d_in, const int* in_sizes, int n_in,
                              void* d_out, int out_size, void* d_ws, size_t ws_size,
                              hipStream_t stream) {
  const float* x   = (const float*)d_in[0];
  const float* wr  = (const float*)d_in[1];
  const float* br  = (const float*)d_in[2];
  const float* wn  = (const float*)d_in[3];
  const float* bn  = (const float*)d_in[4];
  const float* eps = (const float*)d_in[5];
  float* out = (float*)d_out;
  float* wsp = (float*)d_ws;  // 256 blocks * 16 floats = 16 KB partials

  router_main_k<<<NBLK, 1024, 0, stream>>>(x, wr, br, wn, bn, eps, out, wsp);
  router_aux_k<<<1, 256, 0, stream>>>(wsp, out + AUX_OFF);
}

// Round 8
// 76.437 us; speedup vs baseline: 10.1884x; 10.1884x over previous
//
#include <hip/hip_runtime.h>
#include <math.h>

// NoisyTopkRouter: B=4 S=4096 D=2048 E=16 K=2, TEMPERATURE=1. rows = 16384.
// out layout (fp32): router_output [16384*16] | indices-as-float [16384*2] | aux_loss [1]
// Round 8: 256 blocks x 64 rows, 16 waves x 128-d slice, 1024-thread blocks.
//  - KEY FIX: amdgpu_waves_per_eu(4,4). Empirical r5/r6/r7: backend sets VGPR
//    budget from LDS-implied occupancy (64KB LDS -> 2 blocks/CU -> 8 waves/EU
//    -> 64-VGPR cap -> spill). Pinning 4 waves/EU gives budget 128.
//  - R=8 rows/thread, C=4 cols/thread; W ping-pong wp0[4]/wp1[4] (named arrays,
//    static indices), group G+2 loads issued right after group G consumes slot.
//  - x dbuf LDS [2][64][8] per wave, register prefetch, no barriers in main loop.

#define DDIM 2048
#define NEXP 16
#define RPB 64             // rows per block
#define WAVE_D 128         // d-slice per wave (16 waves cover 2048)
#define NCHNK 16           // 8-d chunks per wave slice
#define IDX_OFF 262144
#define AUX_OFF 294912
#define NBLK 256

__global__ __attribute__((amdgpu_waves_per_eu(4, 4))) __launch_bounds__(1024)
void router_main_k(
    const float* __restrict__ x, const float* __restrict__ wr,
    const float* __restrict__ br, const float* __restrict__ wn,
    const float* __restrict__ bn, const float* __restrict__ eps,
    float* __restrict__ out, float* __restrict__ wsp) {
  __shared__ float smem[16384];  // 65536 B: 16 x-dbuf regions / 8 reduce regions

  const int tid  = threadIdx.x;
  const int wave = tid >> 6;
  const int lane = tid & 63;
  const int rg   = lane >> 3;        // 0..7 -> rows {rg + 8i}, i = 0..7
  const int q    = lane & 7;         // col group: q<4 route cols 4q..; q>=4 noise
  const int row_base = blockIdx.x * RPB;

  float* xregion = smem + wave * 1024;   // [2][64][8] dbuf x slice

  // ---- x staging map: lane covers f4 #lane and #(lane+64) of each 128-f4 chunk
  const float* xg0 = x + (size_t)(row_base + (lane >> 1)) * DDIM + wave * WAVE_D + (lane & 1) * 4;
  const float* xg1 = xg0 + (size_t)32 * DDIM;
  const int ls0 = lane * 4;
  const int ls1 = lane * 4 + 256;

  // ---- per-lane W pointer (route for q<4, noise for q>=4)
  const float* wbase = (q < 4 ? wr : wn) + (size_t)(wave * WAVE_D) * NEXP + (q & 3) * 4;

  float4 acc[8];
  #pragma unroll
  for (int i = 0; i < 8; ++i) acc[i] = make_float4(0.f, 0.f, 0.f, 0.f);

  float4 wp0[4], wp1[4];   // ping-pong W pipeline, named arrays -> static regs
  float4 xp0, xp1;

  // ---- prologue: W groups 0,1 + x chunk 0 ----
  #pragma unroll
  for (int j = 0; j < 4; ++j) wp0[j] = *(const float4*)(wbase + j * NEXP);
  #pragma unroll
  for (int j = 0; j < 4; ++j) wp1[j] = *(const float4*)(wbase + (4 + j) * NEXP);
  xp0 = *(const float4*)(xg0);
  xp1 = *(const float4*)(xg1);
  *(float4*)(xregion + ls0) = xp0;
  *(float4*)(xregion + ls1) = xp1;

#define FMA_ROW(WPA, OFF, i) { \
    const float4 xv = *(const float4*)(xb + (rg + 8 * (i)) * 8 + (OFF)); \
    acc[i].x = fmaf(xv.w, WPA[3].x, fmaf(xv.z, WPA[2].x, fmaf(xv.y, WPA[1].x, fmaf(xv.x, WPA[0].x, acc[i].x)))); \
    acc[i].y = fmaf(xv.w, WPA[3].y, fmaf(xv.z, WPA[2].y, fmaf(xv.y, WPA[1].y, fmaf(xv.x, WPA[0].y, acc[i].y)))); \
    acc[i].z = fmaf(xv.w, WPA[3].z, fmaf(xv.z, WPA[2].z, fmaf(xv.y, WPA[1].z, fmaf(xv.x, WPA[0].z, acc[i].z)))); \
    acc[i].w = fmaf(xv.w, WPA[3].w, fmaf(xv.z, WPA[2].w, fmaf(xv.y, WPA[1].w, fmaf(xv.x, WPA[0].w, acc[i].w)))); }

  for (int k = 0; k < NCHNK; ++k) {
    const float* xb = xregion + (k & 1) * 512;
    // x prefetch chunk k+1 (written to other buffer at end of this chunk)
    if (k + 1 < NCHNK) {
      xp0 = *(const float4*)(xg0 + (k + 1) * 8);
      xp1 = *(const float4*)(xg1 + (k + 1) * 8);
    }
    // group 2k (d-offset 0 in chunk) consumes wp0
    #pragma unroll
    for (int i = 0; i < 8; ++i) FMA_ROW(wp0, 0, i);
    // refill wp0 with group 2k+2 (first 4 d of next chunk)
    if (k + 1 < NCHNK) {
      const float* wl = wbase + (size_t)(8 * k + 8) * NEXP;
      #pragma unroll
      for (int j = 0; j < 4; ++j) wp0[j] = *(const float4*)(wl + j * NEXP);
    }
    // group 2k+1 (d-offset 4) consumes wp1
    #pragma unroll
    for (int i = 0; i < 8; ++i) FMA_ROW(wp1, 4, i);
    // refill wp1 with group 2k+3
    if (k + 1 < NCHNK) {
      const float* wl = wbase + (size_t)(8 * k + 12) * NEXP;
      #pragma unroll
      for (int j = 0; j < 4; ++j) wp1[j] = *(const float4*)(wl + j * NEXP);
      float* xw = xregion + ((k + 1) & 1) * 512;
      *(float4*)(xw + ls0) = xp0;
      *(float4*)(xw + ls1) = xp1;
    }
  }

  // ---- 16-wave tree reduction over 8 x [64][32] regions (swizzled col ^ row) ----
  const int psw = (q ^ rg) << 2;

#define DUMP_R(Rg) { float* pr = smem + (Rg) * 2048; \
    _Pragma("unroll") for (int i = 0; i < 8; ++i) \
      *(float4*)(pr + (rg + 8 * i) * 32 + psw) = acc[i]; }
#define ADD_R(Rg) { const float* pr = smem + (Rg) * 2048; \
    _Pragma("unroll") for (int i = 0; i < 8; ++i) { \
      float4 a = *(const float4*)(pr + (rg + 8 * i) * 32 + psw); \
      acc[i].x += a.x; acc[i].y += a.y; acc[i].z += a.z; acc[i].w += a.w; } }

  __syncthreads();
  if (wave >= 8) DUMP_R(wave - 8);
  __syncthreads();
  if (wave < 8)  ADD_R(wave);
  __syncthreads();
  if (wave >= 4 && wave < 8) DUMP_R(wave - 4);
  __syncthreads();
  if (wave < 4)  ADD_R(wave);
  __syncthreads();
  if (wave >= 2 && wave < 4) DUMP_R(wave - 2);
  __syncthreads();
  if (wave < 2)  ADD_R(wave);
  __syncthreads();
  if (wave == 1) DUMP_R(0);
  __syncthreads();

  // ---- wave 0: final add, dump, per-row epilogue (64 rows on 64 lanes) ----
  if (wave == 0) {
    ADD_R(0);
    DUMP_R(0);   // same-wave ds_write -> ds_read: compiler inserts lgkmcnt waits

    const int row_l = lane;
    const int row_g = row_base + row_l;
    float c[32];
    #pragma unroll
    for (int g = 0; g < 8; ++g) {
      float4 a = *(const float4*)(smem + row_l * 32 + ((g ^ (row_l & 7)) << 2));
      c[g * 4 + 0] = a.x; c[g * 4 + 1] = a.y; c[g * 4 + 2] = a.z; c[g * 4 + 3] = a.w;
    }

    float brv[16], bnv[16], ev[16];
    #pragma unroll
    for (int g = 0; g < 4; ++g) {
      *(float4*)(brv + g * 4) = *(const float4*)(br + g * 4);
      *(float4*)(bnv + g * 4) = *(const float4*)(bn + g * 4);
      *(float4*)(ev  + g * 4) = *(const float4*)(eps + (size_t)row_g * NEXP + g * 4);
    }

    float s[16];
    #pragma unroll
    for (int e = 0; e < 16; ++e) {
      float lg = c[e] + brv[e];
      float nz = c[16 + e] + bnv[e];
      float sp = fmaxf(nz, 0.f) + log1pf(expf(-fabsf(nz)));  // stable softplus
      s[e] = lg + ev[e] * sp;                                 // TEMPERATURE == 1
    }

    // top-2 (ties -> lowest index, matching lax.top_k)
    float b1 = s[0]; int i1 = 0;
    #pragma unroll
    for (int e = 1; e < 16; ++e) { if (s[e] > b1) { b1 = s[e]; i1 = e; } }
    float b2 = -INFINITY; int i2 = 0;
    #pragma unroll
    for (int e = 0; e < 16; ++e) { if (e != i1 && s[e] > b2) { b2 = s[e]; i2 = e; } }

    float t2 = expf(b2 - b1);
    float p1 = 1.f / (1.f + t2);
    float p2 = t2 / (1.f + t2);

    float v[16];
    #pragma unroll
    for (int e = 0; e < 16; ++e)
      v[e] = (e == i1) ? p1 : ((e == i2) ? p2 : 0.f);

    float* orow = out + (size_t)row_g * NEXP;
    *(float4*)(orow + 0)  = make_float4(v[0], v[1], v[2], v[3]);
    *(float4*)(orow + 4)  = make_float4(v[4], v[5], v[6], v[7]);
    *(float4*)(orow + 8)  = make_float4(v[8], v[9], v[10], v[11]);
    *(float4*)(orow + 12) = make_float4(v[12], v[13], v[14], v[15]);

    float* oidx = out + IDX_OFF + (size_t)row_g * 2;
    *(float2*)oidx = make_float2((float)i1, (float)i2);

    // per-block expert-prob sums over 64 rows (full-wave butterfly)
    #pragma unroll
    for (int m = 1; m < 64; m <<= 1) {
      #pragma unroll
      for (int e = 0; e < 16; ++e) v[e] += __shfl_xor(v[e], m, 64);
    }
    if (lane == 0) {
      float* wpo = wsp + (size_t)blockIdx.x * 16;
      *(float4*)(wpo + 0)  = make_float4(v[0], v[1], v[2], v[3]);
      *(float4*)(wpo + 4)  = make_float4(v[4], v[5], v[6], v[7]);
      *(float4*)(wpo + 8)  = make_float4(v[8], v[9], v[10], v[11]);
      *(float4*)(wpo + 12) = make_float4(v[12], v[13], v[14], v[15]);
    }
  }
}

__global__ void router_aux_k(const float* __restrict__ wsp, float* __restrict__ out_aux) {
  __shared__ float red[16][17];
  __shared__ float sq[16];
  const int t = threadIdx.x;
  const int e = t & 15;
  const int g = t >> 4;
  float ssum = 0.f;
  #pragma unroll
  for (int b = 0; b < 16; ++b) ssum += wsp[(size_t)(g * 16 + b) * 16 + e];
  red[g][e] = ssum;
  __syncthreads();
  if (t < 16) {
    float tot = 0.f;
    #pragma unroll
    for (int gg = 0; gg < 16; ++gg) tot += red[gg][t];
    float diff = tot * (1.f / 16384.f) - 0.0625f;
    sq[t] = diff * diff;
  }
  __syncthreads();
  if (t == 0) {
    float a = 0.f;
    #pragma unroll
    for (int i = 0; i < 16; ++i) a += sq[i];
    *out_aux = a;
  }
}

extern "C" void kernel_launch(void* const* d_in, const int* in_sizes, int n_in,
                              void* d_out, int out_size, void* d_ws, size_t ws_size,
                              hipStream_t stream) {
  const float* x   = (const float*)d_in[0];
  const float* wr  = (const float*)d_in[1];
  const float* br  = (const float*)d_in[2];
  const float* wn  = (const float*)d_in[3];
  const float* bn  = (const float*)d_in[4];
  const float* eps = (const float*)d_in[5];
  float* out = (float*)d_out;
  float* wsp = (float*)d_ws;  // 256 blocks * 16 floats = 16 KB partials

  router_main_k<<<NBLK, 1024, 0, stream>>>(x, wr, br, wn, bn, eps, out, wsp);
  router_aux_k<<<1, 256, 0, stream>>>(wsp, out + AUX_OFF);
}

// Round 9
// 52.018 us; speedup vs baseline: 14.9712x; 1.4694x over previous
//
#include <hip/hip_runtime.h>
#include <math.h>

// NoisyTopkRouter: B=4 S=4096 D=2048 E=16 K=2, TEMPERATURE=1. rows = 16384.
// out layout (fp32): router_output [16384*16] | indices-as-float [16384*2] | aux_loss [1]
// Round 9: 256 blocks x 64 rows, 8 waves x 256-d slice, 512-thread blocks.
//  - VGPR-budget rule (fitted r3/r5/r6/r7/r8): budget = 512 / (floor(160/LDS_KB)
//    * block_waves / 4). 512thr + 64KB LDS -> 2 blk x 8 waves = 4 waves/EU
//    -> budget 128 >= demand ~95. (1024-thr blocks can never exceed 64.)
//  - R=8 rows x C=4 cols/thread; W ping-pong wp0[4]/wp1[4] from global (L2-hot).
//  - x dbuf LDS [2][64][16] per wave, XOR-swizzled quad g^(row>>1): 8 rg-lanes
//    hit 8 distinct bank-quads -> conflict-free reads. Reg-prefetch staging,
//    no barriers in main loop.

#define DDIM 2048
#define NEXP 16
#define RPB 64             // rows per block
#define WAVE_D 256         // d-slice per wave (8 waves cover 2048)
#define NCHNK 16           // 16-d chunks per wave slice
#define IDX_OFF 262144
#define AUX_OFF 294912
#define NBLK 256

__global__ __launch_bounds__(512) void router_main_k(
    const float* __restrict__ x, const float* __restrict__ wr,
    const float* __restrict__ br, const float* __restrict__ wn,
    const float* __restrict__ bn, const float* __restrict__ eps,
    float* __restrict__ out, float* __restrict__ wsp) {
  __shared__ float smem[16384];  // 65536 B: 8 wave regions x 2048 floats

  const int tid  = threadIdx.x;
  const int wave = tid >> 6;
  const int lane = tid & 63;
  const int rg   = lane >> 3;        // 0..7 -> rows {rg + 8i}, i = 0..7
  const int q    = lane & 7;         // col group: q<4 route cols 4q..; q>=4 noise
  const int sw   = rg >> 1;          // read-side LDS quad swizzle
  const int row_base = blockIdx.x * RPB;

  float* xregion = smem + wave * 2048;   // [2][64][16] dbuf x slice

  // ---- x staging map: lane -> (srow = lane>>2, quad = lane&3), t adds 16 rows
  const int srow  = lane >> 2;
  const int squad = lane & 3;
  const float* xsrc = x + (size_t)(row_base + srow) * DDIM + wave * WAVE_D + squad * 4;
  const int lwoff = srow * 16 + ((squad ^ ((srow >> 1) & 3)) << 2);

  // ---- per-lane W pointer (route for q<4, noise for q>=4)
  const float* wbase = (q < 4 ? wr : wn) + (size_t)(wave * WAVE_D) * NEXP + (q & 3) * 4;

  float4 acc[8];
  #pragma unroll
  for (int i = 0; i < 8; ++i) acc[i] = make_float4(0.f, 0.f, 0.f, 0.f);

  float4 wp0[4], wp1[4];   // ping-pong W pipeline (named arrays -> static regs)
  float4 xp[4];

  // ---- prologue: W groups 0,1 + x chunk 0 into buffer 0 ----
  #pragma unroll
  for (int j = 0; j < 4; ++j) wp0[j] = *(const float4*)(wbase + j * NEXP);
  #pragma unroll
  for (int j = 0; j < 4; ++j) wp1[j] = *(const float4*)(wbase + 64 + j * NEXP);
  #pragma unroll
  for (int t = 0; t < 4; ++t) xp[t] = *(const float4*)(xsrc + (size_t)t * 16 * DDIM);
  #pragma unroll
  for (int t = 0; t < 4; ++t) *(float4*)(xregion + lwoff + t * 256) = xp[t];

#define FMA_ROW(WPA, GG, i) { \
    const float4 xv = *(const float4*)(xb + (rg + 8 * (i)) * 16 + (((GG) ^ sw) << 2)); \
    acc[i].x = fmaf(xv.w, WPA[3].x, fmaf(xv.z, WPA[2].x, fmaf(xv.y, WPA[1].x, fmaf(xv.x, WPA[0].x, acc[i].x)))); \
    acc[i].y = fmaf(xv.w, WPA[3].y, fmaf(xv.z, WPA[2].y, fmaf(xv.y, WPA[1].y, fmaf(xv.x, WPA[0].y, acc[i].y)))); \
    acc[i].z = fmaf(xv.w, WPA[3].z, fmaf(xv.z, WPA[2].z, fmaf(xv.y, WPA[1].z, fmaf(xv.x, WPA[0].z, acc[i].z)))); \
    acc[i].w = fmaf(xv.w, WPA[3].w, fmaf(xv.z, WPA[2].w, fmaf(xv.y, WPA[1].w, fmaf(xv.x, WPA[0].w, acc[i].w)))); }

  for (int k = 0; k < NCHNK; ++k) {
    const float* xb = xregion + (k & 1) * 1024;
    // x prefetch chunk k+1 (issued early; HBM latency hides under 4 groups)
    if (k + 1 < NCHNK) {
      #pragma unroll
      for (int t = 0; t < 4; ++t)
        xp[t] = *(const float4*)(xsrc + (size_t)t * 16 * DDIM + (k + 1) * 16);
    }
    // gg=0: consume wp0, refill wp0 <- group 4k+2 (always valid, <=63)
    #pragma unroll
    for (int i = 0; i < 8; ++i) FMA_ROW(wp0, 0, i);
    { const float* wl = wbase + (size_t)(4 * k + 2) * 64;
      #pragma unroll
      for (int j = 0; j < 4; ++j) wp0[j] = *(const float4*)(wl + j * NEXP); }
    // gg=1: consume wp1, refill wp1 <- group 4k+3 (always valid, <=63)
    #pragma unroll
    for (int i = 0; i < 8; ++i) FMA_ROW(wp1, 1, i);
    { const float* wl = wbase + (size_t)(4 * k + 3) * 64;
      #pragma unroll
      for (int j = 0; j < 4; ++j) wp1[j] = *(const float4*)(wl + j * NEXP); }
    // gg=2: consume wp0, refill wp0 <- group 4k+4 (guard: stay in wave slice)
    #pragma unroll
    for (int i = 0; i < 8; ++i) FMA_ROW(wp0, 2, i);
    if (k + 1 < NCHNK) {
      const float* wl = wbase + (size_t)(4 * k + 4) * 64;
      #pragma unroll
      for (int j = 0; j < 4; ++j) wp0[j] = *(const float4*)(wl + j * NEXP);
    }
    // gg=3: consume wp1, refill wp1 <- group 4k+5; write x chunk k+1
    #pragma unroll
    for (int i = 0; i < 8; ++i) FMA_ROW(wp1, 3, i);
    if (k + 1 < NCHNK) {
      const float* wl = wbase + (size_t)(4 * k + 5) * 64;
      #pragma unroll
      for (int j = 0; j < 4; ++j) wp1[j] = *(const float4*)(wl + j * NEXP);
      float* xw = xregion + ((k + 1) & 1) * 1024;
      #pragma unroll
      for (int t = 0; t < 4; ++t) *(float4*)(xw + lwoff + t * 256) = xp[t];
    }
  }

  // ---- 8-wave tree reduction over [64][32] regions (swizzled col q^rg) ----
  const int psw = (q ^ rg) << 2;

#define DUMP_R(Rg) { float* pr = smem + (Rg) * 2048; \
    _Pragma("unroll") for (int i = 0; i < 8; ++i) \
      *(float4*)(pr + (rg + 8 * i) * 32 + psw) = acc[i]; }
#define ADD_R(Rg) { const float* pr = smem + (Rg) * 2048; \
    _Pragma("unroll") for (int i = 0; i < 8; ++i) { \
      float4 a = *(const float4*)(pr + (rg + 8 * i) * 32 + psw); \
      acc[i].x += a.x; acc[i].y += a.y; acc[i].z += a.z; acc[i].w += a.w; } }

  __syncthreads();
  if (wave >= 4) DUMP_R(wave - 4);
  __syncthreads();
  if (wave < 4)  ADD_R(wave);
  __syncthreads();
  if (wave >= 2 && wave < 4) DUMP_R(wave - 2);
  __syncthreads();
  if (wave < 2)  ADD_R(wave);
  __syncthreads();
  if (wave == 1) DUMP_R(0);
  __syncthreads();

  // ---- wave 0: final add, dump, per-row epilogue (64 rows on 64 lanes) ----
  if (wave == 0) {
    ADD_R(0);
    DUMP_R(0);   // same-wave ds_write -> ds_read: compiler inserts lgkmcnt waits

    const int row_l = lane;
    const int row_g = row_base + row_l;
    float c[32];
    #pragma unroll
    for (int g = 0; g < 8; ++g) {
      float4 a = *(const float4*)(smem + row_l * 32 + ((g ^ (row_l & 7)) << 2));
      c[g * 4 + 0] = a.x; c[g * 4 + 1] = a.y; c[g * 4 + 2] = a.z; c[g * 4 + 3] = a.w;
    }

    float brv[16], bnv[16], ev[16];
    #pragma unroll
    for (int g = 0; g < 4; ++g) {
      *(float4*)(brv + g * 4) = *(const float4*)(br + g * 4);
      *(float4*)(bnv + g * 4) = *(const float4*)(bn + g * 4);
      *(float4*)(ev  + g * 4) = *(const float4*)(eps + (size_t)row_g * NEXP + g * 4);
    }

    float s[16];
    #pragma unroll
    for (int e = 0; e < 16; ++e) {
      float lg = c[e] + brv[e];
      float nz = c[16 + e] + bnv[e];
      float sp = fmaxf(nz, 0.f) + log1pf(expf(-fabsf(nz)));  // stable softplus
      s[e] = lg + ev[e] * sp;                                 // TEMPERATURE == 1
    }

    // top-2 (ties -> lowest index, matching lax.top_k)
    float b1 = s[0]; int i1 = 0;
    #pragma unroll
    for (int e = 1; e < 16; ++e) { if (s[e] > b1) { b1 = s[e]; i1 = e; } }
    float b2 = -INFINITY; int i2 = 0;
    #pragma unroll
    for (int e = 0; e < 16; ++e) { if (e != i1 && s[e] > b2) { b2 = s[e]; i2 = e; } }

    float t2 = expf(b2 - b1);
    float p1 = 1.f / (1.f + t2);
    float p2 = t2 / (1.f + t2);

    float v[16];
    #pragma unroll
    for (int e = 0; e < 16; ++e)
      v[e] = (e == i1) ? p1 : ((e == i2) ? p2 : 0.f);

    float* orow = out + (size_t)row_g * NEXP;
    *(float4*)(orow + 0)  = make_float4(v[0], v[1], v[2], v[3]);
    *(float4*)(orow + 4)  = make_float4(v[4], v[5], v[6], v[7]);
    *(float4*)(orow + 8)  = make_float4(v[8], v[9], v[10], v[11]);
    *(float4*)(orow + 12) = make_float4(v[12], v[13], v[14], v[15]);

    float* oidx = out + IDX_OFF + (size_t)row_g * 2;
    *(float2*)oidx = make_float2((float)i1, (float)i2);

    // per-block expert-prob sums over 64 rows (full-wave butterfly)
    #pragma unroll
    for (int m = 1; m < 64; m <<= 1) {
      #pragma unroll
      for (int e = 0; e < 16; ++e) v[e] += __shfl_xor(v[e], m, 64);
    }
    if (lane == 0) {
      float* wpo = wsp + (size_t)blockIdx.x * 16;
      *(float4*)(wpo + 0)  = make_float4(v[0], v[1], v[2], v[3]);
      *(float4*)(wpo + 4)  = make_float4(v[4], v[5], v[6], v[7]);
      *(float4*)(wpo + 8)  = make_float4(v[8], v[9], v[10], v[11]);
      *(float4*)(wpo + 12) = make_float4(v[12], v[13], v[14], v[15]);
    }
  }
}

__global__ void router_aux_k(const float* __restrict__ wsp, float* __restrict__ out_aux) {
  __shared__ float red[16][17];
  __shared__ float sq[16];
  const int t = threadIdx.x;
  const int e = t & 15;
  const int g = t >> 4;
  float ssum = 0.f;
  #pragma unroll
  for (int b = 0; b < 16; ++b) ssum += wsp[(size_t)(g * 16 + b) * 16 + e];
  red[g][e] = ssum;
  __syncthreads();
  if (t < 16) {
    float tot = 0.f;
    #pragma unroll
    for (int gg = 0; gg < 16; ++gg) tot += red[gg][t];
    float diff = tot * (1.f / 16384.f) - 0.0625f;
    sq[t] = diff * diff;
  }
  __syncthreads();
  if (t == 0) {
    float a = 0.f;
    #pragma unroll
    for (int i = 0; i < 16; ++i) a += sq[i];
    *out_aux = a;
  }
}

extern "C" void kernel_launch(void* const* d_in, const int* in_sizes, int n_in,
                              void* d_out, int out_size, void* d_ws, size_t ws_size,
                              hipStream_t stream) {
  const float* x   = (const float*)d_in[0];
  const float* wr  = (const float*)d_in[1];
  const float* br  = (const float*)d_in[2];
  const float* wn  = (const float*)d_in[3];
  const float* bn  = (const float*)d_in[4];
  const float* eps = (const float*)d_in[5];
  float* out = (float*)d_out;
  float* wsp = (float*)d_ws;  // 256 blocks * 16 floats = 16 KB partials

  router_main_k<<<NBLK, 512, 0, stream>>>(x, wr, br, wn, bn, eps, out, wsp);
  router_aux_k<<<1, 256, 0, stream>>>(wsp, out + AUX_OFF);
}